// Round 1
// baseline (179.878 us; speedup 1.0000x reference)
//
#include <hip/hip_runtime.h>
#include <hip/hip_fp16.h>
#include <math.h>

#define N_NODES 50000
#define N_EDGES 800000
#define D_FEAT 128

#define BSHIFT 5
#define BNODES 32                                  // nodes per bucket (pow2)
#define NBUCK ((N_NODES + BNODES - 1) / BNODES)    // 1563
#define BCAP 768                                   // edges/bucket cap (mean 512 + 11 sigma)
#define SLOT_CAP 64                                // max degree per node (mean 16)

#define PART_BLOCKS 256
#define PART_CHUNK (N_EDGES / PART_BLOCKS)         // 3125

typedef __attribute__((ext_vector_type(4))) _Float16 half4;

#if __has_builtin(__builtin_amdgcn_exp2f)
#define EXP2F(a) __builtin_amdgcn_exp2f(a)
#else
#define EXP2F(a) exp2f(a)
#endif
#if __has_builtin(__builtin_amdgcn_rcpf)
#define RCPF(a) __builtin_amdgcn_rcpf(a)
#else
#define RCPF(a) (1.0f / (a))
#endif

// ---------------- fused fp16 convert + max partials ----------------
__global__ void __launch_bounds__(256) k_cvtmax(const float* __restrict__ x,
                                                half4* __restrict__ x16,
                                                float* __restrict__ partials) {
    const float4* x4 = (const float4*)x;
    const int total4 = N_NODES * D_FEAT / 4;
    float m = -INFINITY;
    for (int i = blockIdx.x * blockDim.x + threadIdx.x; i < total4; i += gridDim.x * blockDim.x) {
        float4 v = x4[i];
        m = fmaxf(m, fmaxf(fmaxf(v.x, v.y), fmaxf(v.z, v.w)));
        half4 h;
        h.x = (_Float16)v.x; h.y = (_Float16)v.y; h.z = (_Float16)v.z; h.w = (_Float16)v.w;
        x16[i] = h;
    }
    for (int off = 32; off > 0; off >>= 1)
        m = fmaxf(m, __shfl_down(m, off, 64));
    __shared__ float smem[4];
    int lane = threadIdx.x & 63, wid = threadIdx.x >> 6;
    if (lane == 0) smem[wid] = m;
    __syncthreads();
    if (threadIdx.x == 0)
        partials[blockIdx.x] = fmaxf(fmaxf(smem[0], smem[1]), fmaxf(smem[2], smem[3]));
}

// ---------------- partition by row-bucket; fused degree atomics + max finalize ----------------
__global__ void __launch_bounds__(512) k_part(const int* __restrict__ row,
                                              const int* __restrict__ col,
                                              int* __restrict__ gcur_row,
                                              int* __restrict__ deg,
                                              int2* __restrict__ be_row,
                                              const float* __restrict__ partials,
                                              float* __restrict__ maxval) {
    __shared__ int h_row[NBUCK];
    __shared__ float sm8[8];
    // former k_max2, folded into block 0 (partials ready: prior kernel in-stream)
    if (blockIdx.x == 0) {
        float m = partials[threadIdx.x];   // 512 threads, 512 partials
        for (int off = 32; off > 0; off >>= 1)
            m = fmaxf(m, __shfl_down(m, off, 64));
        if ((threadIdx.x & 63) == 0) sm8[threadIdx.x >> 6] = m;
    }
    for (int i = threadIdx.x; i < NBUCK; i += 512) h_row[i] = 0;
    __syncthreads();   // uniform across all blocks
    if (blockIdx.x == 0 && threadIdx.x == 0) {
        float m = sm8[0];
        #pragma unroll
        for (int i = 1; i < 8; ++i) m = fmaxf(m, sm8[i]);
        maxval[0] = m;
    }
    int e0 = blockIdx.x * PART_CHUNK;
    // sweep 1: count rows only
    for (int e = e0 + threadIdx.x; e < e0 + PART_CHUNK; e += 512)
        atomicAdd(&h_row[row[e] >> BSHIFT], 1);
    __syncthreads();
    // reserve: coalesced global atomics; LDS -> absolute cursors
    for (int i = threadIdx.x; i < NBUCK; i += 512) {
        int base_r = atomicAdd(&gcur_row[i], h_row[i]);
        h_row[i] = i * BCAP + base_r;
    }
    __syncthreads();
    // sweep 2: scatter by row-bucket + exact in-degree via global atomics
    for (int e = e0 + threadIdx.x; e < e0 + PART_CHUNK; e += 512) {
        int r = row[e], c = col[e];
        atomicAdd(&deg[c], 1);
        int pr = atomicAdd(&h_row[r >> BSHIFT], 1);
        if (pr < (r >> BSHIFT) * BCAP + BCAP) be_row[pr] = make_int2(r, c);
    }
}

// ---------------- fused slot-build (LDS) + aggregation, fp16 gathers ----------------
// One block per 32-node bucket. 256 threads = 8 groups x 32; thread owns 4 feats.
__global__ void __launch_bounds__(256) k_agg(const half4* __restrict__ x16,
                                             const float* __restrict__ x,
                                             const int* __restrict__ gcur_row,
                                             const int2* __restrict__ be_row,
                                             const int* __restrict__ deg,
                                             const float* __restrict__ maxval,
                                             const float* __restrict__ eps_p,
                                             const float* __restrict__ p_p,
                                             float* __restrict__ out) {
    __shared__ int s_cnt[BNODES];
    __shared__ int s_slot[BNODES][SLOT_CAP];     // 8 KB
    __shared__ float s_disv[BNODES][SLOT_CAP];   // 8 KB
    int b = blockIdx.x;
    if (threadIdx.x < BNODES) s_cnt[threadIdx.x] = 0;
    __syncthreads();
    int ecnt = min(gcur_row[b], BCAP);
    int base = b * BCAP;
    for (int k = threadIdx.x; k < ecnt; k += 256) {
        int2 e = be_row[base + k];
        int ln = e.x & (BNODES - 1);
        int pos = atomicAdd(&s_cnt[ln], 1);
        if (pos < SLOT_CAP) {
            s_slot[ln][pos] = e.y;
            s_disv[ln][pos] = rsqrtf((float)deg[e.y]);  // deg[c] >= 1 by construction
        }
    }
    __syncthreads();

    int g = threadIdx.x >> 5;   // node group 0..7
    int t = threadIdx.x & 31;   // float4 feat group
    const float L2E = 1.44269504088896f;
    float pp = 2.0f / (1.0f + __expf(-p_p[0]));
    float ppl = pp * L2E;                 // exp(pp*x - M) == exp2(ppl*x - Ml)
    float Ml  = pp * maxval[0] * L2E;
    float ke  = 1.0f + eps_p[0];
    const float4* x4 = (const float4*)x;

    for (int ln = g; ln < BNODES; ln += 8) {
        int n = (b << BSHIFT) + ln;
        if (n >= N_NODES) continue;
        int cnt = min(s_cnt[ln], SLOT_CAP);
        int dni = deg[n];
        float dn = (dni > 0) ? rsqrtf((float)dni) : 0.0f;
        float4 S = make_float4(0.f, 0.f, 0.f, 0.f);
        float4 T = make_float4(0.f, 0.f, 0.f, 0.f);
        #pragma unroll 4
        for (int j = 0; j < cnt; ++j) {
            int c = s_slot[ln][j];
            float nr = dn * s_disv[ln][j];
            half4 hv = x16[c * 32 + t];
            float x0 = (float)hv.x, x1 = (float)hv.y, x2 = (float)hv.z, x3 = (float)hv.w;
            float e0 = EXP2F(fmaf(ppl, x0, -Ml));
            float e1 = EXP2F(fmaf(ppl, x1, -Ml));
            float e2 = EXP2F(fmaf(ppl, x2, -Ml));
            float e3 = EXP2F(fmaf(ppl, x3, -Ml));
            float w0 = nr * e0, w1 = nr * e1, w2 = nr * e2, w3 = nr * e3;
            S.x += w0; S.y += w1; S.z += w2; S.w += w3;
            T.x = fmaf(w0, x0, T.x);
            T.y = fmaf(w1, x1, T.y);
            T.z = fmaf(w2, x2, T.z);
            T.w = fmaf(w3, x3, T.w);
        }
        float4 xn = x4[n * 32 + t];
        float4 o;
        o.x = T.x * RCPF(S.x + 1e-6f) + ke * xn.x;
        o.y = T.y * RCPF(S.y + 1e-6f) + ke * xn.y;
        o.z = T.z * RCPF(S.z + 1e-6f) + ke * xn.z;
        o.w = T.w * RCPF(S.w + 1e-6f) + ke * xn.w;
        ((float4*)out)[n * 32 + t] = o;
    }
}

extern "C" void kernel_launch(void* const* d_in, const int* in_sizes, int n_in,
                              void* d_out, int out_size, void* d_ws, size_t ws_size,
                              hipStream_t stream) {
    const float* x   = (const float*)d_in[0];
    const int*   ei  = (const int*)d_in[1];   // [2, E]: row = ei[0:E], col = ei[E:2E]
    const float* eps = (const float*)d_in[2];
    const float* p   = (const float*)d_in[3];
    float* out = (float*)d_out;

    const int* row = ei;
    const int* col = ei + N_EDGES;

    // Workspace layout (byte offsets):
    //   gcur_row[NBUCK] | deg[N] | maxval[1] | partials[512] | pad
    //   | x16[N*D halves, 12.8MB] | be_row[NBUCK*BCAP int2, 9.6MB]   total ~22.6 MB
    char* ws = (char*)d_ws;
    int*   gcur_row = (int*)ws;
    int*   deg      = (int*)(ws + 4 * NBUCK);
    float* maxval   = (float*)(ws + 4 * (NBUCK + N_NODES));
    float* partials = (float*)(ws + 4 * (NBUCK + N_NODES + 1));
    size_t off = 4 * (size_t)(NBUCK + N_NODES + 1 + 512);
    off = (off + 15) & ~(size_t)15;
    half4* x16      = (half4*)(ws + off);
    off += (size_t)N_NODES * D_FEAT * 2;               // 12.8 MB
    int2*  be_row   = (int2*)(ws + off);               // 9.6 MB

    // zero bucket cursors + degree (adjacent -> one memset)
    hipMemsetAsync(ws, 0, 4 * (NBUCK + N_NODES), stream);

    k_cvtmax<<<512, 256, 0, stream>>>(x, x16, partials);
    k_part<<<PART_BLOCKS, 512, 0, stream>>>(row, col, gcur_row, deg, be_row, partials, maxval);
    k_agg<<<NBUCK, 256, 0, stream>>>(x16, x, gcur_row, be_row, deg, maxval, eps, p, out);
}